// Round 6
// baseline (623.631 us; speedup 1.0000x reference)
//
#include <hip/hip_runtime.h>
#include <hip/hip_bf16.h>
#include <math.h>

#define D_DIM 512
#define LX 2048
#define LY 2048
#define NB 8

typedef float f32x4 __attribute__((ext_vector_type(4)));
typedef __bf16 bf16x8 __attribute__((ext_vector_type(8)));

__device__ __forceinline__ unsigned short f2bf_rn(float f) {
    unsigned u = __float_as_uint(f);
    unsigned r = (u + 0x7fffu + ((u >> 16) & 1u)) >> 16;
    return (unsigned short)r;
}
__device__ __forceinline__ float bf2f(unsigned short h) {
    return __uint_as_float(((unsigned)h) << 16);
}
__device__ __forceinline__ void async16(void* lds, const void* g) {
    __builtin_amdgcn_global_load_lds(
        (const __attribute__((address_space(1))) void*)g,
        (__attribute__((address_space(3))) void*)lds, 16, 0, 0);
}
__device__ __forceinline__ bf16x8 ldfrag(const char* p) {
    return *(const bf16x8*)p;
}

// ---------------------------------------------------------------------------
// prep_k: fused prologue (unchanged from R5).
// ---------------------------------------------------------------------------
__global__ __launch_bounds__(256) void prep_k(
    const float* __restrict__ x, const float* __restrict__ y,
    const float* __restrict__ Wb,
    unsigned short* __restrict__ xfh, unsigned short* __restrict__ xfl,
    unsigned short* __restrict__ yfh, unsigned short* __restrict__ yfl,
    unsigned short* __restrict__ wfh, unsigned short* __restrict__ wfl,
    unsigned short* __restrict__ xtf)
{
    __shared__ unsigned short T2[64][72];
    const int blk = blockIdx.x, tid = threadIdx.x;

    if (blk < 8320) {
        const float* src; unsigned short *dh, *dl; int base;
        if (blk < 4096)      { src = x;  dh = xfh; dl = xfl; base = blk; }
        else if (blk < 8192) { src = y;  dh = yfh; dl = yfl; base = blk - 4096; }
        else                 { src = Wb; dh = wfh; dl = wfl; base = blk - 8192; }
        int fbid = base * 4 + (tid >> 6);
        int lane = tid & 63;
        int r16 = fbid >> 4, k32 = fbid & 15;
        int row = r16 * 16 + (lane & 15);
        int col = k32 * 32 + (lane >> 4) * 8;
        const float* s = src + (size_t)row * D_DIM + col;
        float4 v0 = *(const float4*)s;
        float4 v1 = *(const float4*)(s + 4);
        float vv[8] = {v0.x, v0.y, v0.z, v0.w, v1.x, v1.y, v1.z, v1.w};
        unsigned hh[4], ll[4];
        #pragma unroll
        for (int k = 0; k < 4; ++k) {
            unsigned short ha = f2bf_rn(vv[2*k]),   hb = f2bf_rn(vv[2*k+1]);
            unsigned short la = f2bf_rn(vv[2*k]   - bf2f(ha));
            unsigned short lb = f2bf_rn(vv[2*k+1] - bf2f(hb));
            hh[k] = (unsigned)ha | ((unsigned)hb << 16);
            ll[k] = (unsigned)la | ((unsigned)lb << 16);
        }
        size_t off = (size_t)fbid * 512 + lane * 8;
        *(uint4*)(dh + off) = make_uint4(hh[0], hh[1], hh[2], hh[3]);
        *(uint4*)(dl + off) = make_uint4(ll[0], ll[1], ll[2], ll[3]);
    } else {
        int idx = blk - 8320;
        int ct = idx & 31, dt = (idx >> 5) & 7, b = idx >> 8;
        const float* xb = x + (size_t)b * LX * D_DIM;
        int rc = tid >> 4;
        int d4 = (tid & 15) * 4;
        #pragma unroll
        for (int i = 0; i < 4; ++i) {
            int cl = rc + i * 16;
            float4 v = *(const float4*)(xb + (size_t)(ct * 64 + cl) * D_DIM + dt * 64 + d4);
            T2[d4 + 0][cl] = f2bf_rn(v.x);
            T2[d4 + 1][cl] = f2bf_rn(v.y);
            T2[d4 + 2][cl] = f2bf_rn(v.z);
            T2[d4 + 3][cl] = f2bf_rn(v.w);
        }
        __syncthreads();
        #pragma unroll
        for (int si = 0; si < 2; ++si) {
            int s = tid + si * 256;
            int fb = s >> 6, lane = s & 63;
            int dd16l = fb >> 1, c32l = fb & 1;
            int ddl = dd16l * 16 + (lane & 15);
            int cl  = c32l * 32 + (lane >> 4) * 8;
            uint4 v = *(const uint4*)&T2[ddl][cl];
            size_t off = ((size_t)((b * 32 + dt * 4 + dd16l) * 64 + (ct * 2 + c32l)) * 64 + lane) * 8;
            *(uint4*)(xtf + off) = v;
        }
    }
}

// ---------------------------------------------------------------------------
// k1: xw = x @ Wb^T, 3-term hi/lo MFMA, dbuf K-loop (unchanged from R5).
// ---------------------------------------------------------------------------
__global__ __launch_bounds__(256, 2) void xw_mfma_k(
    const unsigned short* __restrict__ xfh, const unsigned short* __restrict__ xfl,
    const unsigned short* __restrict__ wfh, const unsigned short* __restrict__ wfl,
    unsigned short* __restrict__ xwfh, unsigned short* __restrict__ xwfl)
{
    __shared__ char smem[49152];
    const int tid = threadIdx.x, lane = tid & 63, w = tid >> 6;
    const int Mt = blockIdx.x, Nt = blockIdx.y;

    f32x4 acc[2][4];
    #pragma unroll
    for (int m = 0; m < 2; ++m)
        #pragma unroll
        for (int n = 0; n < 4; ++n) acc[m][n] = (f32x4){0.f, 0.f, 0.f, 0.f};

    auto stage = [&](int kc, int buf) {
        char* sb = smem + buf * 24576;
        #pragma unroll
        for (int i = 0; i < 4; ++i) {
            int s = w + 4 * i;
            int c16l = s >> 1, h = s & 1;
            size_t fb = ((size_t)(Mt * 8 + c16l)) * 16 + kc;
            const unsigned short* src = (h ? xfl : xfh) + fb * 512 + lane * 8;
            async16(sb + h * 8192 + c16l * 1024 + lane * 16, src);
        }
        #pragma unroll
        for (int i = 0; i < 2; ++i) {
            int s = w + 4 * i;
            int n16l = s >> 1, h = s & 1;
            size_t fb = ((size_t)(Nt * 4 + n16l)) * 16 + kc;
            const unsigned short* src = (h ? wfl : wfh) + fb * 512 + lane * 8;
            async16(sb + 16384 + h * 4096 + n16l * 1024 + lane * 16, src);
        }
    };

    stage(0, 0);
    __syncthreads();
    for (int kc = 0; kc < 16; ++kc) {
        if (kc < 15) stage(kc + 1, (kc + 1) & 1);
        char* sb = smem + (kc & 1) * 24576;
        bf16x8 ah[2], al[2], bh[4], bl[4];
        #pragma unroll
        for (int m = 0; m < 2; ++m) {
            int c16l = w * 2 + m;
            ah[m] = ldfrag(sb + c16l * 1024 + lane * 16);
            al[m] = ldfrag(sb + 8192 + c16l * 1024 + lane * 16);
        }
        #pragma unroll
        for (int n = 0; n < 4; ++n) {
            bh[n] = ldfrag(sb + 16384 + n * 1024 + lane * 16);
            bl[n] = ldfrag(sb + 20480 + n * 1024 + lane * 16);
        }
        #pragma unroll
        for (int m = 0; m < 2; ++m)
            #pragma unroll
            for (int n = 0; n < 4; ++n) {
                acc[m][n] = __builtin_amdgcn_mfma_f32_16x16x32_bf16(ah[m], bh[n], acc[m][n], 0, 0, 0);
                acc[m][n] = __builtin_amdgcn_mfma_f32_16x16x32_bf16(ah[m], bl[n], acc[m][n], 0, 0, 0);
                acc[m][n] = __builtin_amdgcn_mfma_f32_16x16x32_bf16(al[m], bh[n], acc[m][n], 0, 0, 0);
            }
        __syncthreads();
    }

    float* E = (float*)smem;
    const int q = lane >> 4, c15 = lane & 15;
    #pragma unroll
    for (int m = 0; m < 2; ++m)
        #pragma unroll
        for (int n = 0; n < 4; ++n)
            #pragma unroll
            for (int r = 0; r < 4; ++r)
                E[(w * 32 + m * 16 + q * 4 + r) * 68 + n * 16 + c15] = acc[m][n][r];
    __syncthreads();
    #pragma unroll
    for (int i = 0; i < 4; ++i) {
        int s = tid + i * 256;
        int c16l = s >> 7, e32l = (s >> 6) & 1, lp = s & 63;
        int row = c16l * 16 + (lp & 15), col = e32l * 32 + (lp >> 4) * 8;
        const float* sp = E + row * 68 + col;
        unsigned hh[4], ll[4];
        #pragma unroll
        for (int k = 0; k < 4; ++k) {
            float a = sp[2 * k], bq = sp[2 * k + 1];
            unsigned short ha = f2bf_rn(a), hb = f2bf_rn(bq);
            unsigned short la = f2bf_rn(a - bf2f(ha)), lb = f2bf_rn(bq - bf2f(hb));
            hh[k] = (unsigned)ha | ((unsigned)hb << 16);
            ll[k] = (unsigned)la | ((unsigned)lb << 16);
        }
        size_t fb = (size_t)(Mt * 8 + c16l) * 16 + (Nt * 2 + e32l);
        *(uint4*)(xwfh + fb * 512 + lp * 8) = make_uint4(hh[0], hh[1], hh[2], hh[3]);
        *(uint4*)(xwfl + fb * 512 + lp * 8) = make_uint4(ll[0], ll[1], ll[2], ll[3]);
    }
}

// ---------------------------------------------------------------------------
// k2: flash6 — 512 threads, j-tile 32, c-tile 512, 2 blocks/CU.
// Wave w: S stripe 32j x 64c (c = w*64..), 3-term hi/lo; PV d-slice 64 (d=w*64..).
// Single-buffered K32 chunks (stage -> B -> compute -> B); 2nd block on the CU
// covers the drains. PV: 16 c32 chunks, Xt dbuf in chunk-buf halves; Pf dbuf
// (2 x 4 KB), group g (c64) written by wave g.
// LDS 78 KB: chunk [0,69632) = XWh 32K | XWl 32K | Yh 2K | Yl 2K;
//            Pf0 @69632, Pf1 @73728, red_max @77824, red_sum @78848.
// ---------------------------------------------------------------------------
__global__ __launch_bounds__(512, 4) void flash6_k(
    const unsigned short* __restrict__ yfh, const unsigned short* __restrict__ yfl,
    const unsigned short* __restrict__ xwfh, const unsigned short* __restrict__ xwfl,
    const unsigned short* __restrict__ xtf, float* __restrict__ out)
{
    __shared__ char smem[79872];
    const int tid = threadIdx.x, lane = tid & 63, w = tid >> 6;   // w 0..7
    const int jt = blockIdx.x, b = blockIdx.y;
    const int q = lane >> 4, c15 = lane & 15;
    float* red_max = (float*)(smem + 77824);
    float* red_sum = (float*)(smem + 78848);

    f32x4 o[2][4];
    #pragma unroll
    for (int m = 0; m < 2; ++m)
        #pragma unroll
        for (int n = 0; n < 4; ++n) o[m][n] = (f32x4){0.f, 0.f, 0.f, 0.f};
    float m_run[2][4], l_run[2][4];
    #pragma unroll
    for (int m = 0; m < 2; ++m)
        #pragma unroll
        for (int r = 0; r < 4; ++r) { m_run[m][r] = -INFINITY; l_run[m][r] = 0.f; }

    auto stage_s = [&](int xt, int kc) {
        #pragma unroll
        for (int i = 0; i < 8; ++i) {                 // XW: 64 segs (32 c16 x hi/lo)
            int s = w + 8 * i;
            int c16l = s >> 1, h = s & 1;
            size_t fb = ((size_t)(b * 128 + xt * 32 + c16l)) * 16 + kc;
            const unsigned short* src = (h ? xwfl : xwfh) + fb * 512 + lane * 8;
            async16(smem + h * 32768 + c16l * 1024 + lane * 16, src);
        }
        if (w < 4) {                                  // Y: 4 segs (2 j16 x hi/lo)
            int j16l = w & 1, h = w >> 1;
            size_t fb = ((size_t)(b * 128 + jt * 2 + j16l)) * 16 + kc;
            const unsigned short* src = (h ? yfl : yfh) + fb * 512 + lane * 8;
            async16(smem + 65536 + h * 2048 + j16l * 1024 + lane * 16, src);
        }
    };
    auto stage_x = [&](int xt, int cc) {              // Xt c32 -> 32 KB half (cc&1)
        char* xb = smem + (cc & 1) * 32768;
        #pragma unroll
        for (int i = 0; i < 4; ++i) {
            int dd16 = w + 8 * i;
            size_t off = (((size_t)(b * 32 + dd16)) * 64 + (xt * 16 + cc)) * 512 + lane * 8;
            async16(xb + dd16 * 1024 + lane * 16, xtf + off);
        }
    };
    auto write_pf = [&](f32x4 (&sa)[2][4], int g) {   // wave g's P -> Pf[g&1]
        unsigned short* Pf = (unsigned short*)(smem + 69632 + (g & 1) * 4096);
        #pragma unroll
        for (int m = 0; m < 2; ++m)
            #pragma unroll
            for (int n = 0; n < 4; ++n)
                #pragma unroll
                for (int r = 0; r < 4; ++r) {
                    int cH = n >> 1;
                    int co = (n & 1) * 16 + c15;
                    int lp = (q * 4 + r) + 16 * (co >> 3);
                    Pf[(m * 2 + cH) * 512 + lp * 8 + (co & 7)] = f2bf_rn(sa[m][n][r]);
                }
    };

    for (int xt = 0; xt < 4; ++xt) {
        f32x4 sa[2][4];
        #pragma unroll
        for (int m = 0; m < 2; ++m)
            #pragma unroll
            for (int n = 0; n < 4; ++n) sa[m][n] = (f32x4){0.f, 0.f, 0.f, 0.f};

        // ---- S: K=512 in 16 chunks of 32; stage -> B -> compute -> B ----
        for (int kc = 0; kc < 16; ++kc) {
            stage_s(xt, kc);
            __syncthreads();                          // drain (other block computes)
            bf16x8 ah[2], al[2];
            #pragma unroll
            for (int m = 0; m < 2; ++m) {
                ah[m] = ldfrag(smem + 65536 + m * 1024 + lane * 16);
                al[m] = ldfrag(smem + 67584 + m * 1024 + lane * 16);
            }
            #pragma unroll
            for (int n = 0; n < 4; ++n) {
                int c16l = w * 4 + n;
                bf16x8 bh = ldfrag(smem + c16l * 1024 + lane * 16);
                bf16x8 bl = ldfrag(smem + 32768 + c16l * 1024 + lane * 16);
                #pragma unroll
                for (int m = 0; m < 2; ++m) {
                    sa[m][n] = __builtin_amdgcn_mfma_f32_16x16x32_bf16(ah[m], bh, sa[m][n], 0, 0, 0);
                    sa[m][n] = __builtin_amdgcn_mfma_f32_16x16x32_bf16(ah[m], bl, sa[m][n], 0, 0, 0);
                    sa[m][n] = __builtin_amdgcn_mfma_f32_16x16x32_bf16(al[m], bh, sa[m][n], 0, 0, 0);
                }
            }
            __syncthreads();                          // reads done before next stage
        }

        stage_x(xt, 0);                               // prefetch Xt c32 #0 early

        // ---- online softmax (rows j = m*16 + q*4 + r within the 32) ----
        float pmax[2][4];
        #pragma unroll
        for (int m = 0; m < 2; ++m)
            #pragma unroll
            for (int r = 0; r < 4; ++r)
                pmax[m][r] = fmaxf(fmaxf(sa[m][0][r], sa[m][1][r]),
                                   fmaxf(sa[m][2][r], sa[m][3][r]));
        #pragma unroll
        for (int d = 1; d < 16; d <<= 1)
            #pragma unroll
            for (int m = 0; m < 2; ++m)
                #pragma unroll
                for (int r = 0; r < 4; ++r)
                    pmax[m][r] = fmaxf(pmax[m][r], __shfl_xor(pmax[m][r], d, 64));
        if (c15 == 0) {
            #pragma unroll
            for (int m = 0; m < 2; ++m)
                #pragma unroll
                for (int r = 0; r < 4; ++r)
                    red_max[w * 32 + m * 16 + q * 4 + r] = pmax[m][r];
        }
        __syncthreads();                              // B1
        float mnew[2][4], alpha[2][4];
        #pragma unroll
        for (int m = 0; m < 2; ++m)
            #pragma unroll
            for (int r = 0; r < 4; ++r) {
                int j = m * 16 + q * 4 + r;
                float t = red_max[j];
                #pragma unroll
                for (int ww = 1; ww < 8; ++ww) t = fmaxf(t, red_max[ww * 32 + j]);
                float mn = fmaxf(m_run[m][r], t);
                mnew[m][r] = mn;
                alpha[m][r] = __expf(m_run[m][r] - mn);
                m_run[m][r] = mn;
            }
        float psum[2][4] = {};
        #pragma unroll
        for (int m = 0; m < 2; ++m)
            #pragma unroll
            for (int n = 0; n < 4; ++n)
                #pragma unroll
                for (int r = 0; r < 4; ++r) {
                    float p = __expf(sa[m][n][r] - mnew[m][r]);
                    sa[m][n][r] = p;
                    psum[m][r] += p;
                }
        #pragma unroll
        for (int d = 1; d < 16; d <<= 1)
            #pragma unroll
            for (int m = 0; m < 2; ++m)
                #pragma unroll
                for (int r = 0; r < 4; ++r)
                    psum[m][r] += __shfl_xor(psum[m][r], d, 64);
        if (c15 == 0) {
            #pragma unroll
            for (int m = 0; m < 2; ++m)
                #pragma unroll
                for (int r = 0; r < 4; ++r)
                    red_sum[w * 32 + m * 16 + q * 4 + r] = psum[m][r];
        }
        if (w == 0) write_pf(sa, 0);                  // Pf for group 0
        __syncthreads();                              // B2: red_sum, Pf0, Xt#0 ready
        #pragma unroll
        for (int m = 0; m < 2; ++m)
            #pragma unroll
            for (int r = 0; r < 4; ++r) {
                int j = m * 16 + q * 4 + r;
                float ts = red_sum[j];
                #pragma unroll
                for (int ww = 1; ww < 8; ++ww) ts += red_sum[ww * 32 + j];
                l_run[m][r] = l_run[m][r] * alpha[m][r] + ts;
            }
        #pragma unroll
        for (int m = 0; m < 2; ++m)
            #pragma unroll
            for (int n = 0; n < 4; ++n)
                #pragma unroll
                for (int r = 0; r < 4; ++r) o[m][n][r] *= alpha[m][r];

        // ---- PV: 16 c32 chunks; Xt dbuf halves; Pf[g&1] per c64 group ----
        for (int cc = 0; cc < 16; ++cc) {
            if (cc < 15) stage_x(xt, cc + 1);
            int g = cc >> 1, ch = cc & 1;
            const char* Pfb = (const char*)(smem + 69632 + (g & 1) * 4096);
            char* xb = smem + (cc & 1) * 32768;
            bf16x8 pa[2];
            pa[0] = ldfrag(Pfb + (0 * 2 + ch) * 1024 + lane * 16);
            pa[1] = ldfrag(Pfb + (1 * 2 + ch) * 1024 + lane * 16);
            #pragma unroll
            for (int n = 0; n < 4; ++n) {
                bf16x8 xv = ldfrag(xb + (w * 4 + n) * 1024 + lane * 16);
                o[0][n] = __builtin_amdgcn_mfma_f32_16x16x32_bf16(pa[0], xv, o[0][n], 0, 0, 0);
                o[1][n] = __builtin_amdgcn_mfma_f32_16x16x32_bf16(pa[1], xv, o[1][n], 0, 0, 0);
            }
            if ((cc & 1) && cc < 15 && w == g + 1) write_pf(sa, g + 1);
            __syncthreads();
        }
    }

    // ---- epilogue ----
    #pragma unroll
    for (int m = 0; m < 2; ++m)
        #pragma unroll
        for (int r = 0; r < 4; ++r) {
            float inv = 1.0f / l_run[m][r];
            int j = jt * 32 + m * 16 + q * 4 + r;
            #pragma unroll
            for (int n = 0; n < 4; ++n) {
                int dd = w * 64 + n * 16 + c15;
                out[((size_t)(b * 2048 + j)) * 512 + dd] = o[m][n][r] * inv;
            }
        }
}

// ---------------------------------------------------------------------------
// Fallback fp32 path if ws_size is too small for the fast path.
// ---------------------------------------------------------------------------
__global__ __launch_bounds__(256) void xw_gemm_fb(
    const float* __restrict__ x, const float* __restrict__ Wb, float* __restrict__ xw)
{
    __shared__ float As[16][68];
    __shared__ float Bs[16][68];
    const int tid = threadIdx.x;
    const int bm = blockIdx.x * 64, bn = blockIdx.y * 64;
    const int tm = (tid & 15) * 4, tn = (tid >> 4) * 4;
    const int lrow = tid >> 2, lk = (tid & 3) * 4;
    const float* ag = x  + (size_t)(bm + lrow) * D_DIM + lk;
    const float* bg = Wb + (size_t)(bn + lrow) * D_DIM + lk;
    float acc[4][4] = {};
    for (int kt = 0; kt < D_DIM; kt += 16) {
        const float4 av = *(const float4*)(ag + kt);
        const float4 bv = *(const float4*)(bg + kt);
        __syncthreads();
        As[lk+0][lrow] = av.x; As[lk+1][lrow] = av.y; As[lk+2][lrow] = av.z; As[lk+3][lrow] = av.w;
        Bs[lk+0][lrow] = bv.x; Bs[lk+1][lrow] = bv.y; Bs[lk+2][lrow] = bv.z; Bs[lk+3][lrow] = bv.w;
        __syncthreads();
        #pragma unroll
        for (int k = 0; k < 16; ++k) {
            const float4 a = *(const float4*)&As[k][tm];
            const float4 bq = *(const float4*)&Bs[k][tn];
            const float* ap = (const float*)&a;
            const float* bp = (const float*)&bq;
            #pragma unroll
            for (int i = 0; i < 4; ++i)
                #pragma unroll
                for (int jj = 0; jj < 4; ++jj)
                    acc[i][jj] = fmaf(ap[i], bp[jj], acc[i][jj]);
        }
    }
    #pragma unroll
    for (int i = 0; i < 4; ++i)
        *(float4*)&xw[(size_t)(bm + tm + i) * D_DIM + bn + tn] =
            make_float4(acc[i][0], acc[i][1], acc[i][2], acc[i][3]);
}

__global__ __launch_bounds__(256) void flash_fb(
    const float* __restrict__ x, const float* __restrict__ y,
    const float* __restrict__ xw, float* __restrict__ out)
{
    __shared__ float Yl[16][516];
    __shared__ float XWl[64][68];
    __shared__ float Pl[16][68];
    __shared__ float Xl[8][512];
    const int tid = threadIdx.x, b = blockIdx.y, jtb = blockIdx.x;
    const int j = tid >> 4, tc = tid & 15, c0 = tc * 4;
    {
        const float* yg = y + (size_t)(b * LY + jtb * 16 + j) * D_DIM;
        #pragma unroll
        for (int ii = 0; ii < 8; ++ii)
            *(float4*)&Yl[j][tc * 4 + 64 * ii] = *(const float4*)(yg + tc * 4 + 64 * ii);
    }
    float4 o[8];
    #pragma unroll
    for (int ii = 0; ii < 8; ++ii) o[ii] = make_float4(0.f, 0.f, 0.f, 0.f);
    float m = -INFINITY, l = 0.f;
    const size_t xbase = (size_t)b * LX * D_DIM;
    for (int xtt = 0; xtt < LX / 64; ++xtt) {
        float sa[4] = {0.f, 0.f, 0.f, 0.f};
        for (int kcc = 0; kcc < D_DIM; kcc += 64) {
            const int sc = tid >> 2, skq = (tid & 3) * 4;
            const float* xwg = xw + xbase + (size_t)(xtt * 64 + sc) * D_DIM + kcc + skq;
            const float4 t0 = *(const float4*)(xwg + 0);
            const float4 t1 = *(const float4*)(xwg + 16);
            const float4 t2 = *(const float4*)(xwg + 32);
            const float4 t3 = *(const float4*)(xwg + 48);
            __syncthreads();
            XWl[skq+ 0][sc]=t0.x; XWl[skq+ 1][sc]=t0.y; XWl[skq+ 2][sc]=t0.z; XWl[skq+ 3][sc]=t0.w;
            XWl[skq+16][sc]=t1.x; XWl[skq+17][sc]=t1.y; XWl[skq+18][sc]=t1.z; XWl[skq+19][sc]=t1.w;
            XWl[skq+32][sc]=t2.x; XWl[skq+33][sc]=t2.y; XWl[skq+34][sc]=t2.z; XWl[skq+35][sc]=t2.w;
            XWl[skq+48][sc]=t3.x; XWl[skq+49][sc]=t3.y; XWl[skq+50][sc]=t3.z; XWl[skq+51][sc]=t3.w;
            __syncthreads();
            #pragma unroll
            for (int k4 = 0; k4 < 16; ++k4) {
                const float4 yv = *(const float4*)&Yl[j][kcc + k4 * 4];
                const float* yp = (const float*)&yv;
                #pragma unroll
                for (int ss = 0; ss < 4; ++ss) {
                    const float4 xv = *(const float4*)&XWl[k4 * 4 + ss][c0];
                    sa[0] = fmaf(yp[ss], xv.x, sa[0]);
                    sa[1] = fmaf(yp[ss], xv.y, sa[1]);
                    sa[2] = fmaf(yp[ss], xv.z, sa[2]);
                    sa[3] = fmaf(yp[ss], xv.w, sa[3]);
                }
            }
        }
        float tmax = fmaxf(fmaxf(sa[0], sa[1]), fmaxf(sa[2], sa[3]));
        #pragma unroll
        for (int ww = 1; ww < 16; ww <<= 1) tmax = fmaxf(tmax, __shfl_xor(tmax, ww, 64));
        const float mnew = fmaxf(m, tmax);
        const float scale = __expf(m - mnew);
        const float p0 = __expf(sa[0] - mnew), p1 = __expf(sa[1] - mnew);
        const float p2 = __expf(sa[2] - mnew), p3 = __expf(sa[3] - mnew);
        float ts = p0 + p1 + p2 + p3;
        #pragma unroll
        for (int ww = 1; ww < 16; ww <<= 1) ts += __shfl_xor(ts, ww, 64);
        l = l * scale + ts; m = mnew;
        #pragma unroll
        for (int ii = 0; ii < 8; ++ii) {
            o[ii].x *= scale; o[ii].y *= scale; o[ii].z *= scale; o[ii].w *= scale;
        }
        *(float4*)&Pl[j][c0] = make_float4(p0, p1, p2, p3);
        for (int ccc = 0; ccc < 8; ++ccc) {
            const int xr = tid >> 5, xq = (tid & 31) * 4;
            const float* xg = x + xbase + (size_t)(xtt * 64 + ccc * 8 + xr) * D_DIM + xq;
            const float4 x0 = *(const float4*)(xg + 0);
            const float4 x1 = *(const float4*)(xg + 128);
            const float4 x2 = *(const float4*)(xg + 256);
            const float4 x3 = *(const float4*)(xg + 384);
            __syncthreads();
            *(float4*)&Xl[xr][xq +   0] = x0; *(float4*)&Xl[xr][xq + 128] = x1;
            *(float4*)&Xl[xr][xq + 256] = x2; *(float4*)&Xl[xr][xq + 384] = x3;
            __syncthreads();
            #pragma unroll
            for (int c = 0; c < 8; ++c) {
                const float pv = Pl[j][ccc * 8 + c];
                #pragma unroll
                for (int ii = 0; ii < 8; ++ii) {
                    const float4 xv = *(const float4*)&Xl[c][tc * 4 + 64 * ii];
                    o[ii].x = fmaf(pv, xv.x, o[ii].x); o[ii].y = fmaf(pv, xv.y, o[ii].y);
                    o[ii].z = fmaf(pv, xv.z, o[ii].z); o[ii].w = fmaf(pv, xv.w, o[ii].w);
                }
            }
        }
    }
    const float inv = 1.0f / l;
    float* og = out + (size_t)(b * LY + jtb * 16 + j) * D_DIM;
    #pragma unroll
    for (int ii = 0; ii < 8; ++ii) {
        float4 v = o[ii];
        v.x *= inv; v.y *= inv; v.z *= inv; v.w *= inv;
        *(float4*)(og + tc * 4 + 64 * ii) = v;
    }
}

// ---------------------------------------------------------------------------
extern "C" void kernel_launch(void* const* d_in, const int* in_sizes, int n_in,
                              void* d_out, int out_size, void* d_ws, size_t ws_size,
                              hipStream_t stream)
{
    const float* x  = (const float*)d_in[0];
    const float* y  = (const float*)d_in[1];
    const float* Wb = (const float*)d_in[2];
    float* out = (float*)d_out;

    const size_t OFF_XFH = 0,         OFF_XFL = 16777216;
    const size_t OFF_YFH = 33554432,  OFF_YFL = 50331648;
    const size_t OFF_XTF = 67108864;
    const size_t OFF_XWH = 83886080,  OFF_XWL = 100663296;
    const size_t OFF_WFH = 117440512, OFF_WFL = 117964800;
    const size_t NEEDED  = 118489088;

    if (ws_size >= NEEDED) {
        char* ws = (char*)d_ws;
        unsigned short* xfh = (unsigned short*)(ws + OFF_XFH);
        unsigned short* xfl = (unsigned short*)(ws + OFF_XFL);
        unsigned short* yfh = (unsigned short*)(ws + OFF_YFH);
        unsigned short* yfl = (unsigned short*)(ws + OFF_YFL);
        unsigned short* xtf = (unsigned short*)(ws + OFF_XTF);
        unsigned short* xwfh = (unsigned short*)(ws + OFF_XWH);
        unsigned short* xwfl = (unsigned short*)(ws + OFF_XWL);
        unsigned short* wfh = (unsigned short*)(ws + OFF_WFH);
        unsigned short* wfl = (unsigned short*)(ws + OFF_WFL);

        prep_k<<<10368, 256, 0, stream>>>(x, y, Wb, xfh, xfl, yfh, yfl, wfh, wfl, xtf);
        dim3 g1(128, 8);
        xw_mfma_k<<<g1, 256, 0, stream>>>(xfh, xfl, wfh, wfl, xwfh, xwfl);
        dim3 g2(64, 8);
        flash6_k<<<g2, 512, 0, stream>>>(yfh, yfl, xwfh, xwfl, xtf, out);
    } else {
        float* xw = (float*)d_ws;
        dim3 g1(NB * LX / 64, D_DIM / 64);
        xw_gemm_fb<<<g1, 256, 0, stream>>>(x, Wb, xw);
        dim3 g2(LY / 16, NB);
        flash_fb<<<g2, 256, 0, stream>>>(x, y, xw, out);
    }
}